// Round 2
// baseline (404.903 us; speedup 1.0000x reference)
//
#include <hip/hip_runtime.h>
#include <hip/hip_bf16.h>

#define D 128

// ---------------- preprocessing ----------------

__global__ void count_kernel(const int* __restrict__ dst, int* __restrict__ counts, int e) {
    int i = blockIdx.x * 256 + threadIdx.x;
    if (i < e) atomicAdd(&counts[dst[i]], 1);
}

__global__ void dinv_kernel(const int* __restrict__ counts, float* __restrict__ dinv, int n) {
    int i = blockIdx.x * 256 + threadIdx.x;
    if (i < n) dinv[i] = rsqrtf((float)(counts[i] + 1));  // +1 self loop, deg>=1
}

// 3-kernel exclusive scan of counts -> row_ptr (N up to 256*2048)
__global__ void scan_part(const int* __restrict__ counts, int* __restrict__ partial, int n) {
    __shared__ int sm[256];
    int b = blockIdx.x, t = threadIdx.x;
    int base = b * 2048 + t * 8;
    int s = 0;
#pragma unroll
    for (int j = 0; j < 8; j++) { int idx = base + j; if (idx < n) s += counts[idx]; }
    sm[t] = s; __syncthreads();
    for (int off = 128; off > 0; off >>= 1) { if (t < off) sm[t] += sm[t + off]; __syncthreads(); }
    if (t == 0) partial[b] = sm[0];
}

__global__ void scan_top(int* partial, int nb) {
    __shared__ int sm[256];
    int t = threadIdx.x;
    int v = (t < nb) ? partial[t] : 0;
    sm[t] = v; __syncthreads();
    for (int off = 1; off < 256; off <<= 1) {
        int u = (t >= off) ? sm[t - off] : 0;
        __syncthreads();
        sm[t] += u;
        __syncthreads();
    }
    if (t < nb) partial[t] = sm[t] - v;  // exclusive
}

__global__ void scan_down(const int* __restrict__ counts, const int* __restrict__ blockoff,
                          int* __restrict__ row_ptr, int n) {
    __shared__ int sm[256];
    int b = blockIdx.x, t = threadIdx.x;
    int base = b * 2048 + t * 8;
    int c[8], local[8];
    int s = 0;
#pragma unroll
    for (int j = 0; j < 8; j++) {
        int idx = base + j;
        c[j] = (idx < n) ? counts[idx] : 0;
        local[j] = s; s += c[j];
    }
    sm[t] = s; __syncthreads();
    int own = s;
    for (int off = 1; off < 256; off <<= 1) {
        int u = (t >= off) ? sm[t - off] : 0;
        __syncthreads();
        sm[t] += u;
        __syncthreads();
    }
    int basev = blockoff[b] + sm[t] - own;
#pragma unroll
    for (int j = 0; j < 8; j++) { int idx = base + j; if (idx < n) row_ptr[idx] = basev + local[j]; }
}

__global__ void fill_kernel(const int* __restrict__ src, const int* __restrict__ dst,
                            const int* __restrict__ row_ptr, int* __restrict__ cursor,
                            const float* __restrict__ dinv, int* __restrict__ csr_src,
                            float* __restrict__ csr_norm, int e) {
    int i = blockIdx.x * 256 + threadIdx.x;
    if (i >= e) return;
    int s = src[i], d = dst[i];
    int pos = row_ptr[d] + atomicAdd(&cursor[d], 1);
    csr_src[pos] = s;
    csr_norm[pos] = dinv[s] * dinv[d];
}

// ---------------- GEMM: Z[n,128] = X[n,128] @ W[128,128] (fp32) ----------------
// block 256 = 8 ty x 32 tx; per block: 32 rows x 128 cols; per thread 4 rows x 4 cols.

__device__ inline void fma4(float4& acc, float s, const float4& wv) {
    acc.x = fmaf(s, wv.x, acc.x);
    acc.y = fmaf(s, wv.y, acc.y);
    acc.z = fmaf(s, wv.z, acc.z);
    acc.w = fmaf(s, wv.w, acc.w);
}

__launch_bounds__(256, 2)
__global__ void gemm128(const float* __restrict__ X, const float* __restrict__ W,
                        float* __restrict__ Z, int nrows) {
    __shared__ float4 sW[128 * 32];  // [k][c4]  64KB
    __shared__ float4 sX[32 * 32];   // [r][k4]  16KB
    int t = threadIdx.x;
    const float4* Wg = (const float4*)W;
#pragma unroll
    for (int i = 0; i < 16; i++) sW[t + 256 * i] = Wg[t + 256 * i];
    long row0 = (long)blockIdx.x * 32;
    const float4* Xg = (const float4*)(X + row0 * D);
    int maxf4 = (int)((long)nrows * 32 - row0 * 32);
#pragma unroll
    for (int i = 0; i < 4; i++) { int idx = t + 256 * i; if (idx < maxf4) sX[idx] = Xg[idx]; }
    __syncthreads();

    int tx = t & 31, ty = t >> 5;
    int r0 = ty * 4;
    float4 acc0 = {0, 0, 0, 0}, acc1 = {0, 0, 0, 0}, acc2 = {0, 0, 0, 0}, acc3 = {0, 0, 0, 0};

    for (int k4 = 0; k4 < 32; k4++) {
        float4 x0 = sX[(r0 + 0) * 32 + k4];
        float4 x1 = sX[(r0 + 1) * 32 + k4];
        float4 x2 = sX[(r0 + 2) * 32 + k4];
        float4 x3 = sX[(r0 + 3) * 32 + k4];
        float4 w0 = sW[(k4 * 4 + 0) * 32 + tx];
        float4 w1 = sW[(k4 * 4 + 1) * 32 + tx];
        float4 w2 = sW[(k4 * 4 + 2) * 32 + tx];
        float4 w3 = sW[(k4 * 4 + 3) * 32 + tx];
        fma4(acc0, x0.x, w0); fma4(acc0, x0.y, w1); fma4(acc0, x0.z, w2); fma4(acc0, x0.w, w3);
        fma4(acc1, x1.x, w0); fma4(acc1, x1.y, w1); fma4(acc1, x1.z, w2); fma4(acc1, x1.w, w3);
        fma4(acc2, x2.x, w0); fma4(acc2, x2.y, w1); fma4(acc2, x2.z, w2); fma4(acc2, x2.w, w3);
        fma4(acc3, x3.x, w0); fma4(acc3, x3.y, w1); fma4(acc3, x3.z, w2); fma4(acc3, x3.w, w3);
    }

    float4* Zg = (float4*)(Z + row0 * D);
    if (row0 + r0 + 0 < nrows) Zg[(r0 + 0) * 32 + tx] = acc0;
    if (row0 + r0 + 1 < nrows) Zg[(r0 + 1) * 32 + tx] = acc1;
    if (row0 + r0 + 2 < nrows) Zg[(r0 + 2) * 32 + tx] = acc2;
    if (row0 + r0 + 3 < nrows) Zg[(r0 + 3) * 32 + tx] = acc3;
}

// ---------------- aggregation: h[v] = relu(dinv[v]^2*z[v] + sum norm*z[src] + b) ----------------
// 32 threads (float4 each) per node; 8 nodes per block.

__global__ void agg_kernel(const float4* __restrict__ z, const int* __restrict__ row_ptr,
                           const int* __restrict__ counts, const int* __restrict__ csr_src,
                           const float* __restrict__ csr_norm, const float* __restrict__ dinv,
                           const float* __restrict__ bias, float4* __restrict__ h, int n) {
    int t = blockIdx.x * 256 + threadIdx.x;
    int v = t >> 5, f = t & 31;
    if (v >= n) return;
    float dv = dinv[v];
    float sw = dv * dv;
    float4 zc = z[(size_t)v * 32 + f];
    float4 acc;
    acc.x = zc.x * sw; acc.y = zc.y * sw; acc.z = zc.z * sw; acc.w = zc.w * sw;
    int start = row_ptr[v], cnt = counts[v];
    for (int i = 0; i < cnt; i++) {
        int s = csr_src[start + i];
        float w = csr_norm[start + i];
        float4 m = z[(size_t)s * 32 + f];
        acc.x = fmaf(w, m.x, acc.x);
        acc.y = fmaf(w, m.y, acc.y);
        acc.z = fmaf(w, m.z, acc.z);
        acc.w = fmaf(w, m.w, acc.w);
    }
    float4 bb = ((const float4*)bias)[f];
    acc.x = fmaxf(acc.x + bb.x, 0.f);
    acc.y = fmaxf(acc.y + bb.y, 0.f);
    acc.z = fmaxf(acc.z + bb.z, 0.f);
    acc.w = fmaxf(acc.w + bb.w, 0.f);
    h[(size_t)v * 32 + f] = acc;
}

// ---------------- FC: out[n,2] = h @ Wfc + bfc ----------------

__global__ void fc_kernel(const float4* __restrict__ h, const float* __restrict__ Wfc,
                          const float* __restrict__ bfc, float* __restrict__ out, int n) {
    int t = blockIdx.x * 256 + threadIdx.x;
    int v = t >> 5, f = t & 31;
    if (v >= n) return;
    float4 hv = h[(size_t)v * 32 + f];
    const float4* W4 = (const float4*)Wfc;
    float4 wa = W4[2 * f];      // {W[4f][0],W[4f][1],W[4f+1][0],W[4f+1][1]}
    float4 wb = W4[2 * f + 1];  // {W[4f+2][0],W[4f+2][1],W[4f+3][0],W[4f+3][1]}
    float a0 = hv.x * wa.x + hv.y * wa.z + hv.z * wb.x + hv.w * wb.z;
    float a1 = hv.x * wa.y + hv.y * wa.w + hv.z * wb.y + hv.w * wb.w;
    for (int off = 16; off > 0; off >>= 1) {
        a0 += __shfl_down(a0, off, 32);
        a1 += __shfl_down(a1, off, 32);
    }
    if (f == 0) {
        out[(size_t)v * 2 + 0] = a0 + bfc[0];
        out[(size_t)v * 2 + 1] = a1 + bfc[1];
    }
}

// ---------------- launch ----------------

extern "C" void kernel_launch(void* const* d_in, const int* in_sizes, int n_in,
                              void* d_out, int out_size, void* d_ws, size_t ws_size,
                              hipStream_t stream) {
    const float* x   = (const float*)d_in[0];
    const int*   ei  = (const int*)d_in[1];
    const float* W1  = (const float*)d_in[2];
    const float* b1  = (const float*)d_in[3];
    const float* W2  = (const float*)d_in[4];
    const float* b2  = (const float*)d_in[5];
    const float* Wfc = (const float*)d_in[6];
    const float* bfc = (const float*)d_in[7];
    float* out = (float*)d_out;

    int n = in_sizes[0] / D;   // 100000
    int e = in_sizes[1] / 2;   // 640000
    const int* src = ei;
    const int* dst = ei + e;

    // workspace layout (all offsets 16B-aligned for these sizes)
    char* ws = (char*)d_ws;
    size_t nb = (size_t)n * 4;
    int*   counts   = (int*)(ws);
    int*   cursor   = (int*)(ws + nb);
    float* dinv     = (float*)(ws + 2 * nb);
    int*   rowptr   = (int*)(ws + 3 * nb);
    int*   partial  = (int*)(ws + 4 * nb);            // 1024 B reserved
    int*   csr_src  = (int*)(ws + 4 * nb + 1024);
    float* csr_norm = (float*)(ws + 4 * nb + 1024 + (size_t)e * 4);
    float* bufA     = (float*)(ws + 4 * nb + 1024 + (size_t)e * 8);
    float* bufB     = bufA + (size_t)n * D;

    hipMemsetAsync(counts, 0, 2 * nb, stream);  // counts + cursor

    int eb = (e + 255) / 256;
    int sb = (n + 2047) / 2048;
    int gb = (n + 31) / 32;
    int ab = ((n * 32) + 255) / 256;

    count_kernel<<<eb, 256, 0, stream>>>(dst, counts, e);
    dinv_kernel<<<(n + 255) / 256, 256, 0, stream>>>(counts, dinv, n);
    scan_part<<<sb, 256, 0, stream>>>(counts, partial, n);
    scan_top<<<1, 256, 0, stream>>>(partial, sb);
    scan_down<<<sb, 256, 0, stream>>>(counts, partial, rowptr, n);
    fill_kernel<<<eb, 256, 0, stream>>>(src, dst, rowptr, cursor, dinv, csr_src, csr_norm, e);

    // layer 1
    gemm128<<<gb, 256, 0, stream>>>(x, W1, bufA, n);
    agg_kernel<<<ab, 256, 0, stream>>>((const float4*)bufA, rowptr, counts, csr_src, csr_norm,
                                       dinv, b1, (float4*)bufB, n);
    // layer 2
    gemm128<<<gb, 256, 0, stream>>>(bufB, W2, bufA, n);
    agg_kernel<<<ab, 256, 0, stream>>>((const float4*)bufA, rowptr, counts, csr_src, csr_norm,
                                       dinv, b2, (float4*)bufB, n);
    // classifier
    fc_kernel<<<ab, 256, 0, stream>>>((const float4*)bufB, Wfc, bfc, out, n);
}